// Round 1
// baseline (352.477 us; speedup 1.0000x reference)
//
#include <hip/hip_runtime.h>
#include <hip/hip_bf16.h>

#define BB 2048
#define TT 128
#define NN (BB*TT)          // 262144
#define NVAL NN

// workspace layout (float offsets)
#define OFF_W0P   2048u       // W0 B-frag pack (16384 bf16)
#define OFF_W1P   10240u      // W1 B-frag pack (65536 bf16)
#define OFF_WQKV  43008u      // attn_in_w B-frag pack
#define OFF_WO    44544u      // attn_out_w B-frag pack
#define OFF_PWHA  49792u      // air Whh f16 A-frag pack (perm rows): 1536 uints
#define OFF_PWHM  51328u      // m   Whh f16 A-frag pack: 1536 uints
#define OFF_PWCA  52864u      // air combined Wih f16 A-frag pack (+bias col): 1536 uints
#define OFF_PWCM  54400u      // m   combined Wih f16 A-frag pack: 1536 uints
#define OFF_BHNA  55936u      // air bhh n-gate (32 f32, natural order)
#define OFF_BHNM  55968u      // m   bhh n-gate (32 f32)
#define OFF_AIRF  83968u      // air_feat bf16: NN*32 shorts = 4194304 floats
#define OFF_MF    4278272u    // m_feat bf16: 2*NN*32 shorts = 8388608 floats
#define OFF_MASK  12666880u   // N*2 mask floats

typedef __attribute__((ext_vector_type(8))) short short8;
typedef __attribute__((ext_vector_type(4))) float f32x4;
typedef _Float16 f16x8 __attribute__((ext_vector_type(8)));
typedef unsigned u32x4 __attribute__((ext_vector_type(4)));

__device__ __forceinline__ unsigned short f2bf(float f) {
    unsigned u = __builtin_bit_cast(unsigned, f);
    u += 0x7FFFu + ((u >> 16) & 1u);       // RNE
    return (unsigned short)(u >> 16);
}
__device__ __forceinline__ unsigned f2h(float f) {
    _Float16 h = (_Float16)f;
    return (unsigned)__builtin_bit_cast(unsigned short, h);
}
__device__ __forceinline__ unsigned pkh2(float a, float b) {
    return (f2h(b) << 16) | f2h(a);
}
__device__ __forceinline__ float fast_rcp(float x) {
    return __builtin_amdgcn_rcpf(x);
}
__device__ __forceinline__ unsigned cvt_pk_bf16(float a, float b) {
    unsigned r;
    asm("v_cvt_pk_bf16_f32 %0, %1, %2" : "=v"(r) : "v"(a), "v"(b));
    return r;
}
__device__ __forceinline__ f32x4 mfma16f(f16x8 a, f16x8 b, f32x4 c) {
    return __builtin_amdgcn_mfma_f32_16x16x32_f16(a, b, c, 0, 0, 0);
}

// ---------------- prep -----------------------------------------------------
__global__ __launch_bounds__(256) void prep_kernel(
    const float* __restrict__ enc_air_W, const float* __restrict__ enc_air_b,
    const float* __restrict__ enc_m_W,   const float* __restrict__ enc_m_b,
    const float* __restrict__ air_Wih,   const float* __restrict__ air_bih,
    const float* __restrict__ m_Wih,     const float* __restrict__ m_bih,
    const float* __restrict__ air_Whh,   const float* __restrict__ m_Whh,
    const float* __restrict__ air_bhh,   const float* __restrict__ m_bhh,
    const float* __restrict__ W0,        const float* __restrict__ W1,
    const float* __restrict__ attn_in_w, const float* __restrict__ attn_out_w,
    float* __restrict__ ws)
{
    int b = blockIdx.x, t = threadIdx.x;
    if (b == 0) {
        // combined biases now folded into the f16 Wc packs (b==43); idle
    } else if (b <= 32) {
        unsigned short* w1p = (unsigned short*)(ws + OFF_W1P);
        int base = ((b-1)*256 + t);
        int lane = base & 63;
        int ctf  = base >> 6;
        int ct   = ctf & 15, s = ctf >> 4;   // s 0..7
        int col = lane & 15, quad = lane >> 4;
        int k0 = s*32 + quad*8;
        int o  = ct*16 + col;
        #pragma unroll
        for (int j = 0; j < 8; j++)
            w1p[base*8 + j] = f2bf(W1[o*256 + k0 + j]);
    } else if (b <= 40) {
        unsigned short* w0p = (unsigned short*)(ws + OFF_W0P);
        int base = ((b-33)*256 + t);
        int lane = base & 63;
        int ctf  = base >> 6;
        int ct   = ctf & 15, s = ctf >> 4;   // s 0..1
        int col = lane & 15, quad = lane >> 4;
        int k0 = s*32 + quad*8;
        int o  = ct*16 + col;
        #pragma unroll
        for (int j = 0; j < 8; j++)
            w0p[base*8 + j] = f2bf(W0[o*64 + k0 + j]);
    } else if (b == 41) { // attention weight packs
        unsigned short* wqkv = (unsigned short*)(ws + OFF_WQKV);
        unsigned short* wop  = (unsigned short*)(ws + OFF_WO);
        for (int slot = t; slot < 512; slot += 256) {
            if (slot < 384) {
                int ct = slot >> 6, lane = slot & 63;
                int col = lane & 15, quad = lane >> 4;
                int o = ct*16 + col;
                #pragma unroll
                for (int j = 0; j < 8; j++)
                    wqkv[slot*8 + j] = f2bf(attn_in_w[o*32 + quad*8 + j]);
            } else {
                int s2 = slot - 384;
                int ct = s2 >> 6, lane = s2 & 63;
                int col = lane & 15, quad = lane >> 4;
                #pragma unroll
                for (int j = 0; j < 8; j++)
                    wop[s2*8 + j] = f2bf(attn_out_w[(ct*16+col)*32 + quad*8 + j]);
            }
        }
    } else if (b == 42) {
        // Whh f16 A-frag packs. 6 tiles per GRU: tile = gate*2+hf (gate r,z,n).
        // A-row rr (= lane&15) holds feature f = (rr>>2)*8 + hf*4 + (rr&3),
        // so D(quad,reg) lands exactly on the h feature its quad must supply
        // for the next-step B-frag (k = quad*8 + hf*4 + reg) -> zero shuffles.
        unsigned* pa = (unsigned*)(ws + OFF_PWHA);
        unsigned* pm = (unsigned*)(ws + OFF_PWHM);
        for (int s = t; s < 3072; s += 256) {
            int s2 = (s < 1536) ? s : s - 1536;
            const float* W = (s < 1536) ? air_Whh : m_Whh;
            unsigned* dst = (s < 1536) ? pa : pm;
            int tile = s2 >> 8;          // 0..5
            int l    = (s2 >> 2) & 63;
            int d    = s2 & 3;           // dword within frag
            int gate = tile >> 1, hfp = tile & 1;
            int rr = l & 15;
            int f  = (rr >> 2)*8 + hfp*4 + (rr & 3);
            int k  = (l >> 4)*8 + d*2;
            int row = gate*32 + f;
            dst[s2] = pkh2(W[row*32 + k], W[row*32 + k + 1]);
        }
    } else { // b == 43: combined input-weight f16 A-frags (+bias in const-1 col)
        unsigned* pa = (unsigned*)(ws + OFF_PWCA);
        unsigned* pm = (unsigned*)(ws + OFF_PWCM);
        for (int s = t; s < 3072; s += 256) {
            bool isA = (s < 1536);
            int s2 = isA ? s : s - 1536;
            unsigned* dst = isA ? pa : pm;
            int tile = s2 >> 8, l = (s2 >> 2) & 63, d = s2 & 3;
            int gate = tile >> 1, hfp = tile & 1;
            int rr = l & 15;
            int f = (rr >> 2)*8 + hfp*4 + (rr & 3);
            int o = gate*32 + f;
            int kb = (l >> 4)*8 + d*2;
            int ni = isA ? 7 : 4;
            float v[2];
            #pragma unroll
            for (int e = 0; e < 2; e++) {
                int k = kb + e;
                float acc = 0.f;
                if (k < ni) {
                    for (int m = 0; m < 32; m++)
                        acc += isA ? air_Wih[o*32+m]*enc_air_W[m*7+k]
                                   : m_Wih[o*32+m]*enc_m_W[m*4+k];
                } else if (k == ni) {
                    acc = isA ? air_bih[o] : m_bih[o];
                    for (int m = 0; m < 32; m++)
                        acc += isA ? air_Wih[o*32+m]*enc_air_b[m]
                                   : m_Wih[o*32+m]*enc_m_b[m];
                    if (gate < 2) acc += isA ? air_bhh[o] : m_bhh[o]; // r,z: fold bhh
                }
                v[e] = acc;
            }
            dst[s2] = pkh2(v[0], v[1]);
        }
        if (t < 32) {
            ws[OFF_BHNA + t] = air_bhh[64 + t];
            ws[OFF_BHNM + t] = m_bhh[64 + t];
        }
    }
}

// ---------------- GRU: 16 rows/wave via f16 MFMA, shuffle-free loop ---------
template<bool AIRT>
__device__ __forceinline__ void gru_tile(
    const float* __restrict__ obs, const float* __restrict__ rnn,
    const float* __restrict__ ws,
    unsigned short* __restrict__ feat, float* __restrict__ mask_f,
    float* __restrict__ nh_out, int tileIdx)
{
    const int lane = threadIdx.x & 63;
    const int col = lane & 15, quad = lane >> 4;
    const bool q0 = (quad == 0);

    const unsigned* pw = (const unsigned*)(ws + (AIRT ? OFF_PWHA : OFF_PWHM));
    const unsigned* pc = (const unsigned*)(ws + (AIRT ? OFF_PWCA : OFF_PWCM));
    f16x8 whf[6], wcf[6];
    #pragma unroll
    for (int i6 = 0; i6 < 6; i6++) {
        whf[i6] = __builtin_bit_cast(f16x8, *(const u32x4*)(pw + i6*256 + lane*4));
        wcf[i6] = __builtin_bit_cast(f16x8, *(const u32x4*)(pc + i6*256 + lane*4));
    }
    const float* bhnp = ws + (AIRT ? OFF_BHNA : OFF_BHNM) + quad*8;
    f32x4 bhn0 = *(const f32x4*)(bhnp);
    f32x4 bhn1 = *(const f32x4*)(bhnp + 4);

    int hbase, brow = 0, slot = 0;
    size_t featOff;
    const float* xptr;
    if (AIRT) {
        int r = tileIdx*16 + col;
        hbase = r*96;
        featOff = (size_t)r*(TT*32);
        xptr = obs + (size_t)r*(TT*15) + 8;
    } else {
        int i = tileIdx*16 + col;
        slot = (i >= BB) ? 1 : 0;
        brow = i - slot*BB;
        hbase = (i >> 1)*96 + 32 + (i & 1)*32;
        featOff = (size_t)i*(TT*32);
        xptr = obs + (size_t)brow*(TT*15) + slot*4;
    }
    unsigned short* featp = feat + featOff + quad*8;

    // h state in D-layout: h0v = features quad*8+0..3, h1v = quad*8+4..7 (per col-row)
    f32x4 h0v = *(const f32x4*)(rnn + hbase + quad*8);
    f32x4 h1v = *(const f32x4*)(rnn + hbase + quad*8 + 4);

    constexpr int NI = AIRT ? 7 : 4;
    float nx[NI];
    #pragma unroll
    for (int u = 0; u < NI; u++) nx[u] = xptr[u];

    #pragma unroll 1
    for (int t = 0; t < TT; t++) {
        float cx[NI];
        #pragma unroll
        for (int u = 0; u < NI; u++) cx[u] = nx[u];
        const int tn = (t < TT-1) ? (t+1)*15 : t*15;   // clamp: never OOB
        #pragma unroll
        for (int u = 0; u < NI; u++) nx[u] = xptr[tn + u];   // prefetch t+1

        if (!AIRT) {
            bool ok = (fabsf(cx[0] - 1.f) <= 1.00001e-5f) &&
                      (fabsf(cx[1])       <= 1e-8f) &&
                      (fabsf(cx[2] - 1.f) <= 1.00001e-5f) &&
                      (fabsf(cx[3])       <= 1e-8f);
            if (q0) mask_f[((size_t)brow*TT + t)*2 + slot] = ok ? 1.f : 0.f;
        }

        // x B-frag: quad0 carries k=0..7 (inputs + const-1 bias col), rest zero
        unsigned xd0, xd1, xd2, xd3;
        if (AIRT) {
            xd0 = pkh2(cx[0], cx[1]); xd1 = pkh2(cx[2], cx[3]);
            xd2 = pkh2(cx[4], cx[5]); xd3 = pkh2(cx[6], 1.0f);
        } else {
            xd0 = pkh2(cx[0], cx[1]); xd1 = pkh2(cx[2], cx[3]);
            xd2 = 0x00003C00u;        xd3 = 0u;     // (1.0h, 0)
        }
        u32x4 xdv;
        xdv[0] = q0 ? xd0 : 0u; xdv[1] = q0 ? xd1 : 0u;
        xdv[2] = q0 ? xd2 : 0u; xdv[3] = q0 ? xd3 : 0u;
        f16x8 xf = __builtin_bit_cast(f16x8, xdv);

        // h B-frag: quad q supplies k = q*8..q*8+7 -> lane-local from h0v/h1v
        u32x4 hdv;
        hdv[0] = pkh2(h0v[0], h0v[1]); hdv[1] = pkh2(h0v[2], h0v[3]);
        hdv[2] = pkh2(h1v[0], h1v[1]); hdv[3] = pkh2(h1v[2], h1v[3]);
        f16x8 hff = __builtin_bit_cast(f16x8, hdv);

        const f32x4 z4 = {0.f, 0.f, 0.f, 0.f};
        f32x4 aR0 = mfma16f(whf[0], hff, mfma16f(wcf[0], xf, z4));
        f32x4 aR1 = mfma16f(whf[1], hff, mfma16f(wcf[1], xf, z4));
        f32x4 aZ0 = mfma16f(whf[2], hff, mfma16f(wcf[2], xf, z4));
        f32x4 aZ1 = mfma16f(whf[3], hff, mfma16f(wcf[3], xf, z4));
        f32x4 aXN0 = mfma16f(wcf[4], xf, z4);
        f32x4 aXN1 = mfma16f(wcf[5], xf, z4);
        f32x4 aHN0 = mfma16f(whf[4], hff, z4);
        f32x4 aHN1 = mfma16f(whf[5], hff, z4);

        #pragma unroll
        for (int s = 0; s < 4; s++) {
            {
                float r  = fast_rcp(1.f + __expf(-aR0[s]));
                float z  = fast_rcp(1.f + __expf(-aZ0[s]));
                float hn = aHN0[s] + bhn0[s];
                float pre = aXN0[s] + r*hn;
                float e2 = __expf(2.f*pre);
                float n  = 1.f - 2.f*fast_rcp(e2 + 1.f);
                h0v[s] = n + z*(h0v[s] - n);
            }
            {
                float r  = fast_rcp(1.f + __expf(-aR1[s]));
                float z  = fast_rcp(1.f + __expf(-aZ1[s]));
                float hn = aHN1[s] + bhn1[s];
                float pre = aXN1[s] + r*hn;
                float e2 = __expf(2.f*pre);
                float n  = 1.f - 2.f*fast_rcp(e2 + 1.f);
                h1v[s] = n + z*(h1v[s] - n);
            }
        }

        // bf16 feat store: 8 contiguous features per lane -> one dwordx4
        u32x4 fw;
        fw[0] = cvt_pk_bf16(h0v[0], h0v[1]); fw[1] = cvt_pk_bf16(h0v[2], h0v[3]);
        fw[2] = cvt_pk_bf16(h1v[0], h1v[1]); fw[3] = cvt_pk_bf16(h1v[2], h1v[3]);
        *(u32x4*)(featp + (size_t)t*32) = fw;
    }
    *(f32x4*)(nh_out + hbase + quad*8)     = h0v;
    *(f32x4*)(nh_out + hbase + quad*8 + 4) = h1v;
}

__global__ __launch_bounds__(64) void gru_kernel(
    const float* __restrict__ obs, const float* __restrict__ rnn,
    const float* __restrict__ ws,
    unsigned short* __restrict__ air_feat, unsigned short* __restrict__ m_feat,
    float* __restrict__ mask_f, float* __restrict__ nh_out)
{
    int g = blockIdx.x;
    if (g < 128) gru_tile<true >(obs, rnn, ws, air_feat, mask_f, nh_out, g);
    else         gru_tile<false>(obs, rnn, ws, m_feat,  mask_f, nh_out, g - 128);
}

// ---------------- fused attention + MLP (bf16 MFMA, ct-split, pipelined) ----
__global__ __launch_bounds__(256) void fused_kernel(
    const unsigned short* __restrict__ air_feat, const unsigned short* __restrict__ m_feat,
    const float* __restrict__ mask_f,
    const unsigned short* __restrict__ wqkv, const float* __restrict__ attn_in_b,
    const unsigned short* __restrict__ wop,  const float* __restrict__ attn_out_b,
    const unsigned short* __restrict__ w0p, const float* __restrict__ b0,
    const unsigned short* __restrict__ w1p, const float* __restrict__ b1,
    const float* __restrict__ outW, const float* __restrict__ outb,
    float* __restrict__ val)
{
    __shared__ unsigned short A1[64*72];   // fusion: air 0-31, attn 32-63 (persists)
    __shared__ unsigned short U[64*264];   // phase1: AM(64*72)+CT(64*40); phase2: A2
    __shared__ float MS[128];
    __shared__ float PS[4][64];

    unsigned short* AM = U;
    unsigned short* CT = U + 64*72;
    unsigned short* A2 = U;

    const int tid  = threadIdx.x;
    const int lane = tid & 63;
    const int strip = tid >> 6;
    const int col  = lane & 15;
    const int quad = lane >> 4;
    const size_t n0 = (size_t)blockIdx.x * 64;

    // ---- attn weight frags: load BEFORE barrier (fly during staging drain)
    short8 wqf[2], wkf[2], wvf[2], wof[2];
    #pragma unroll
    for (int ct = 0; ct < 2; ct++) {
        wqf[ct] = *(const short8*)(wqkv + ((0+ct)*64 + lane)*8);
        wkf[ct] = *(const short8*)(wqkv + ((2+ct)*64 + lane)*8);
        wvf[ct] = *(const short8*)(wqkv + ((4+ct)*64 + lane)*8);
        wof[ct] = *(const short8*)(wop + (ct*64 + lane)*8);
    }

    // ---- stage bf16 feats directly ----
    {
        int row = tid >> 2, c0 = (tid & 3)*8;
        short8 va  = *(const short8*)(air_feat + (n0 + row)*32 + c0);
        *(short8*)&A1[row*72 + c0] = va;
        short8 vm1 = *(const short8*)(m_feat + (n0 + row)*32 + c0);
        *(short8*)&AM[row*72 + c0] = vm1;
        short8 vm2 = *(const short8*)(m_feat + ((size_t)NN + n0 + row)*32 + c0);
        *(short8*)&AM[row*72 + 32 + c0] = vm2;
        if (tid < 128) MS[tid] = mask_f[n0*2 + tid];
    }
    __syncthreads();

    // ---- attention (per-strip) ----
    {
        short8 a_air = *(const short8*)&A1[(strip*16 + col)*72 + quad*8];
        short8 a_m1  = *(const short8*)&AM[(strip*16 + col)*72 + quad*8];
        short8 a_m2  = *(const short8*)&AM[(strip*16 + col)*72 + 32 + quad*8];

        f32x4 q[2], k1[2], k2[2], v1[2], v2[2], ao[2];
        #pragma unroll
        for (int ct = 0; ct < 2; ct++) {
            f32x4 z = (f32x4){0.f,0.f,0.f,0.f};
            q[ct]  = __builtin_amdgcn_mfma_f32_16x16x32_bf16(a_air, wqf[ct], z, 0,0,0);
            k1[ct] = __builtin_amdgcn_mfma_f32_16x16x32_bf16(a_m1,  wkf[ct], z, 0,0,0);
            k2[ct] = __builtin_amdgcn_mfma_f32_16x16x32_bf16(a_m2,  wkf[ct], z, 0,0,0);
            v1[ct] = __builtin_amdgcn_mfma_f32_16x16x32_bf16(a_m1,  wvf[ct], z, 0,0,0);
            v2[ct] = __builtin_amdgcn_mfma_f32_16x16x32_bf16(a_m2,  wvf[ct], z, 0,0,0);
        }
        float bqr[2], bkr[2], bvr[2];
        #pragma unroll
        for (int ct = 0; ct < 2; ct++) {
            bqr[ct] = attn_in_b[ct*16 + col];
            bkr[ct] = attn_in_b[32 + ct*16 + col];
            bvr[ct] = attn_in_b[64 + ct*16 + col];
        }
        float p1s[2][4], p2s[2][4];
        #pragma unroll
        for (int ct = 0; ct < 2; ct++) {
            #pragma unroll
            for (int reg = 0; reg < 4; reg++) {
                float qq = q[ct][reg] + bqr[ct];
                float p1 = qq * (k1[ct][reg] + bkr[ct]);
                float p2 = qq * (k2[ct][reg] + bkr[ct]);
                #pragma unroll
                for (int m = 1; m < 16; m <<= 1) {
                    p1 += __shfl_xor(p1, m, 64);
                    p2 += __shfl_xor(p2, m, 64);
                }
                p1s[ct][reg] = p1; p2s[ct][reg] = p2;
            }
        }
        float bothm[4];
        #pragma unroll
        for (int reg = 0; reg < 4; reg++) {
            int rloc = strip*16 + quad*4 + reg;
            float m0v = MS[rloc*2], m1v = MS[rloc*2 + 1];
            bothm[reg] = (m0v > 0.5f && m1v > 0.5f) ? 1.f : 0.f;
            #pragma unroll
            for (int ct = 0; ct < 2; ct++) {
                float s1 = p1s[ct][reg]*0.25f + (m0v > 0.5f ? -1e9f : 0.f);
                float s2 = p2s[ct][reg]*0.25f + (m1v > 0.5f ? -1e9f : 0.f);
                float mx = fmaxf(s1, s2);
                float e1 = __expf(s1 - mx), e2 = __expf(s2 - mx);
                float inv = fast_rcp(e1 + e2);
                float ctxv = ((v1[ct][reg] + bvr[ct])*e1 +
                              (v2[ct][reg] + bvr[ct])*e2) * inv;
                CT[rloc*40 + ct*16 + col] = f2bf(ctxv);
            }
        }
        short8 a_ctx = *(const short8*)&CT[(strip*16 + col)*40 + quad*8];
        #pragma unroll
        for (int ct = 0; ct < 2; ct++) {
            f32x4 z = (f32x4){0.f,0.f,0.f,0.f};
            ao[ct] = __builtin_amdgcn_mfma_f32_16x16x32_bf16(a_ctx, wof[ct], z, 0,0,0);
        }
        float bor[2] = { attn_out_b[col], attn_out_b[16 + col] };
        #pragma unroll
        for (int reg = 0; reg < 4; reg++) {
            int rloc = strip*16 + quad*4 + reg;
            #pragma unroll
            for (int ct = 0; ct < 2; ct++) {
                float av = ao[ct][reg] + bor[ct];
                av = (bothm[reg] > 0.5f) ? 0.f : av;
                A1[rloc*72 + 32 + ct*16 + col] = f2bf(av);
            }
        }
    }
    __syncthreads();   // attention done; A1 complete; AM/CT now dead

    // per-lane bias / out-weight for this wave's 4 col-tiles
    float b0r[4], b1r[4], owr[4];
    #pragma unroll
    for (int c = 0; c < 4; c++) {
        int ct = strip*4 + c;
        b0r[c] = b0[ct*16 + col];
        b1r[c] = b1[ct*16 + col];
        owr[c] = outW[ct*16 + col];
    }
    const float outb0 = outb[0];

    // ---- layer 1: all 64 rows x this wave's 4 ct, K=64 (pipelined B-frags) --
    f32x4 acc1[4][4];   // [row-strip s][ct-local]
    #pragma unroll
    for (int s = 0; s < 4; s++)
        #pragma unroll
        for (int c = 0; c < 4; c++) acc1[s][c] = (f32x4){0.f,0.f,0.f,0.f};
    {
        short8 bfr[4], nbfr[4];
        #pragma unroll
        for (int c = 0; c < 4; c++)
            bfr[c] = *(const short8*)(w0p + ((0*16 + strip*4 + c)*64 + lane)*8);
        #pragma unroll
        for (int ks = 0; ks < 2; ks++) {
            if (ks < 1) {
                #pragma unroll
                for (int c = 0; c < 4; c++)
                    nbfr[c] = *(const short8*)(w0p + (((ks+1)*16 + strip*4 + c)*64 + lane)*8);
            }
            short8 a[4];
            #pragma unroll
            for (int s = 0; s < 4; s++)
                a[s] = *(const short8*)&A1[(s*16 + col)*72 + ks*32 + quad*8];
            #pragma unroll
            for (int c = 0; c < 4; c++)
                #pragma unroll
                for (int s = 0; s < 4; s++)
                    acc1[s][c] = __builtin_amdgcn_mfma_f32_16x16x32_bf16(a[s], bfr[c], acc1[s][c], 0, 0, 0);
            #pragma unroll
            for (int c = 0; c < 4; c++) bfr[c] = nbfr[c];
        }
    }
    __syncthreads();   // everyone done reading A1/U-phase1 before A2 overwrite
    #pragma unroll
    for (int s = 0; s < 4; s++) {
        #pragma unroll
        for (int c = 0; c < 4; c++) {
            int ct = strip*4 + c;
            #pragma unroll
            for (int reg = 0; reg < 4; reg++) {
                float h = acc1[s][c][reg] + b0r[c];
                h = (h > 0.f) ? h : 0.01f*h;
                A2[(s*16 + quad*4 + reg)*264 + ct*16 + col] = f2bf(h);
            }
        }
    }
    __syncthreads();

    // ---- layer 2: all 64 rows x this wave's 4 ct, K=256 (pipelined) ----
    f32x4 acc2[4][4];
    #pragma unroll
    for (int s = 0; s < 4; s++)
        #pragma unroll
        for (int c = 0; c < 4; c++) acc2[s][c] = (f32x4){0.f,0.f,0.f,0.f};
    {
        short8 bfr[4], nbfr[4];
        #pragma unroll
        for (int c = 0; c < 4; c++)
            bfr[c] = *(const short8*)(w1p + ((0*16 + strip*4 + c)*64 + lane)*8);
        #pragma unroll
        for (int ks = 0; ks < 8; ks++) {
            if (ks < 7) {
                #pragma unroll
                for (int c = 0; c < 4; c++)
                    nbfr[c] = *(const short8*)(w1p + (((ks+1)*16 + strip*4 + c)*64 + lane)*8);
            }
            short8 a[4];
            #pragma unroll
            for (int s = 0; s < 4; s++)
                a[s] = *(const short8*)&A2[(s*16 + col)*264 + ks*32 + quad*8];
            #pragma unroll
            for (int c = 0; c < 4; c++)
                #pragma unroll
                for (int s = 0; s < 4; s++)
                    acc2[s][c] = __builtin_amdgcn_mfma_f32_16x16x32_bf16(a[s], bfr[c], acc2[s][c], 0, 0, 0);
            #pragma unroll
            for (int c = 0; c < 4; c++) bfr[c] = nbfr[c];
        }
    }

    // ---- out layer: partial dot per wave, reduce across col-lanes + waves ----
    #pragma unroll
    for (int s = 0; s < 4; s++) {
        float pv[4];
        #pragma unroll
        for (int reg = 0; reg < 4; reg++) pv[reg] = 0.f;
        #pragma unroll
        for (int c = 0; c < 4; c++) {
            #pragma unroll
            for (int reg = 0; reg < 4; reg++) {
                float h = acc2[s][c][reg] + b1r[c];
                h = (h > 0.f) ? h : 0.01f*h;
                pv[reg] += h*owr[c];
            }
        }
        #pragma unroll
        for (int reg = 0; reg < 4; reg++) {
            #pragma unroll
            for (int m = 1; m < 16; m <<= 1)
                pv[reg] += __shfl_xor(pv[reg], m, 64);
            if (col == 0) PS[strip][s*16 + quad*4 + reg] = pv[reg];
        }
    }
    __syncthreads();
    if (tid < 64)
        val[n0 + tid] = PS[0][tid] + PS[1][tid] + PS[2][tid] + PS[3][tid] + outb0;
}

// ---------------- launch ---------------------------------------------------
extern "C" void kernel_launch(void* const* d_in, const int* in_sizes, int n_in,
                              void* d_out, int out_size, void* d_ws, size_t ws_size,
                              hipStream_t stream) {
    const float* obs        = (const float*)d_in[0];
    const float* rnn        = (const float*)d_in[1];
    const float* enc_air_W  = (const float*)d_in[2];
    const float* enc_air_b  = (const float*)d_in[3];
    const float* enc_m_W    = (const float*)d_in[4];
    const float* enc_m_b    = (const float*)d_in[5];
    const float* air_Wih    = (const float*)d_in[6];
    const float* air_Whh    = (const float*)d_in[7];
    const float* air_bih    = (const float*)d_in[8];
    const float* air_bhh    = (const float*)d_in[9];
    const float* m_Wih      = (const float*)d_in[10];
    const float* m_Whh      = (const float*)d_in[11];
    const float* m_bih      = (const float*)d_in[12];
    const float* m_bhh      = (const float*)d_in[13];
    const float* attn_in_w  = (const float*)d_in[14];
    const float* attn_in_b  = (const float*)d_in[15];
    const float* attn_out_w = (const float*)d_in[16];
    const float* attn_out_b = (const float*)d_in[17];
    const float* mlp_W0     = (const float*)d_in[18];
    const float* mlp_b0     = (const float*)d_in[19];
    const float* mlp_W1     = (const float*)d_in[20];
    const float* mlp_b1     = (const float*)d_in[21];
    const float* out_W      = (const float*)d_in[22];
    const float* out_b      = (const float*)d_in[23];

    float* ws  = (float*)d_ws;
    float* out = (float*)d_out;

    prep_kernel<<<44, 256, 0, stream>>>(enc_air_W, enc_air_b, enc_m_W, enc_m_b,
                                        air_Wih, air_bih, m_Wih, m_bih,
                                        air_Whh, m_Whh, air_bhh, m_bhh,
                                        mlp_W0, mlp_W1, attn_in_w, attn_out_w, ws);

    gru_kernel<<<384, 64, 0, stream>>>(obs, rnn, ws,
                                       (unsigned short*)(ws + OFF_AIRF),
                                       (unsigned short*)(ws + OFF_MF),
                                       ws + OFF_MASK, out + NVAL);

    fused_kernel<<<NN/64, 256, 0, stream>>>((const unsigned short*)(ws + OFF_AIRF),
                                            (const unsigned short*)(ws + OFF_MF),
                                            ws + OFF_MASK,
                                            (const unsigned short*)(ws + OFF_WQKV), attn_in_b,
                                            (const unsigned short*)(ws + OFF_WO),   attn_out_b,
                                            (const unsigned short*)(ws + OFF_W0P), mlp_b0,
                                            (const unsigned short*)(ws + OFF_W1P), mlp_b1,
                                            out_W, out_b, out);
}

// Round 2
// 320.915 us; speedup vs baseline: 1.0983x; 1.0983x over previous
//
#include <hip/hip_runtime.h>
#include <hip/hip_bf16.h>

#define BB 2048
#define TT 128
#define NN (BB*TT)          // 262144
#define NVAL NN

// workspace layout (float offsets)
#define OFF_W0P   2048u       // W0 B-frag pack (16384 bf16)
#define OFF_W1P   10240u      // W1 B-frag pack (65536 bf16)
#define OFF_WQKV  43008u      // attn_in_w B-frag pack
#define OFF_WO    44544u      // attn_out_w B-frag pack
#define OFF_PWHA  49792u      // air Whh f16 A-frag pack (perm rows): 1536 uints
#define OFF_PWHM  51328u      // m   Whh f16 A-frag pack: 1536 uints
#define OFF_PWCA  52864u      // air combined Wih f16 A-frag pack (+bias col): 1536 uints
#define OFF_PWCM  54400u      // m   combined Wih f16 A-frag pack: 1536 uints
#define OFF_BHNA  55936u      // air bhh n-gate (32 f32, natural order)
#define OFF_BHNM  55968u      // m   bhh n-gate (32 f32)
#define OFF_AIRF  83968u      // air_feat bf16: NN*32 shorts = 4194304 floats
#define OFF_MF    4278272u    // m_feat bf16: 2*NN*32 shorts = 8388608 floats
#define OFF_MASK  12666880u   // N*2 mask floats

typedef __attribute__((ext_vector_type(8))) short short8;
typedef __attribute__((ext_vector_type(4))) float f32x4;
typedef _Float16 f16x8 __attribute__((ext_vector_type(8)));
typedef unsigned u32x4 __attribute__((ext_vector_type(4)));

__device__ __forceinline__ unsigned short f2bf(float f) {
    unsigned u = __builtin_bit_cast(unsigned, f);
    u += 0x7FFFu + ((u >> 16) & 1u);       // RNE
    return (unsigned short)(u >> 16);
}
__device__ __forceinline__ unsigned f2h(float f) {
    _Float16 h = (_Float16)f;
    return (unsigned)__builtin_bit_cast(unsigned short, h);
}
__device__ __forceinline__ unsigned pkh2(float a, float b) {
    return (f2h(b) << 16) | f2h(a);
}
__device__ __forceinline__ float fast_rcp(float x) {
    return __builtin_amdgcn_rcpf(x);
}
__device__ __forceinline__ unsigned cvt_pk_bf16(float a, float b) {
    unsigned r;
    asm("v_cvt_pk_bf16_f32 %0, %1, %2" : "=v"(r) : "v"(a), "v"(b));
    return r;
}
__device__ __forceinline__ f32x4 mfma16f(f16x8 a, f16x8 b, f32x4 c) {
    return __builtin_amdgcn_mfma_f32_16x16x32_f16(a, b, c, 0, 0, 0);
}

// ---------------- prep -----------------------------------------------------
__global__ __launch_bounds__(256) void prep_kernel(
    const float* __restrict__ enc_air_W, const float* __restrict__ enc_air_b,
    const float* __restrict__ enc_m_W,   const float* __restrict__ enc_m_b,
    const float* __restrict__ air_Wih,   const float* __restrict__ air_bih,
    const float* __restrict__ m_Wih,     const float* __restrict__ m_bih,
    const float* __restrict__ air_Whh,   const float* __restrict__ m_Whh,
    const float* __restrict__ air_bhh,   const float* __restrict__ m_bhh,
    const float* __restrict__ W0,        const float* __restrict__ W1,
    const float* __restrict__ attn_in_w, const float* __restrict__ attn_out_w,
    float* __restrict__ ws)
{
    int b = blockIdx.x, t = threadIdx.x;
    if (b == 0) {
        // combined biases folded into the f16 Wc packs (b==43); idle
    } else if (b <= 32) {
        unsigned short* w1p = (unsigned short*)(ws + OFF_W1P);
        int base = ((b-1)*256 + t);
        int lane = base & 63;
        int ctf  = base >> 6;
        int ct   = ctf & 15, s = ctf >> 4;   // s 0..7
        int col = lane & 15, quad = lane >> 4;
        int k0 = s*32 + quad*8;
        int o  = ct*16 + col;
        #pragma unroll
        for (int j = 0; j < 8; j++)
            w1p[base*8 + j] = f2bf(W1[o*256 + k0 + j]);
    } else if (b <= 40) {
        unsigned short* w0p = (unsigned short*)(ws + OFF_W0P);
        int base = ((b-33)*256 + t);
        int lane = base & 63;
        int ctf  = base >> 6;
        int ct   = ctf & 15, s = ctf >> 4;   // s 0..1
        int col = lane & 15, quad = lane >> 4;
        int k0 = s*32 + quad*8;
        int o  = ct*16 + col;
        #pragma unroll
        for (int j = 0; j < 8; j++)
            w0p[base*8 + j] = f2bf(W0[o*64 + k0 + j]);
    } else if (b == 41) { // attention weight packs
        unsigned short* wqkv = (unsigned short*)(ws + OFF_WQKV);
        unsigned short* wop  = (unsigned short*)(ws + OFF_WO);
        for (int slot = t; slot < 512; slot += 256) {
            if (slot < 384) {
                int ct = slot >> 6, lane = slot & 63;
                int col = lane & 15, quad = lane >> 4;
                int o = ct*16 + col;
                #pragma unroll
                for (int j = 0; j < 8; j++)
                    wqkv[slot*8 + j] = f2bf(attn_in_w[o*32 + quad*8 + j]);
            } else {
                int s2 = slot - 384;
                int ct = s2 >> 6, lane = s2 & 63;
                int col = lane & 15, quad = lane >> 4;
                #pragma unroll
                for (int j = 0; j < 8; j++)
                    wop[s2*8 + j] = f2bf(attn_out_w[(ct*16+col)*32 + quad*8 + j]);
            }
        }
    } else if (b == 42) {
        // Whh f16 A-frag packs. 6 tiles per GRU: tile = gate*2+hf (gate r,z,n).
        // A-row rr (= lane&15) holds feature f = (rr>>2)*8 + hf*4 + (rr&3),
        // so D(quad,reg) lands exactly on the h feature its quad must supply
        // for the next-step B-frag (k = quad*8 + hf*4 + reg) -> zero shuffles.
        unsigned* pa = (unsigned*)(ws + OFF_PWHA);
        unsigned* pm = (unsigned*)(ws + OFF_PWHM);
        for (int s = t; s < 3072; s += 256) {
            int s2 = (s < 1536) ? s : s - 1536;
            const float* W = (s < 1536) ? air_Whh : m_Whh;
            unsigned* dst = (s < 1536) ? pa : pm;
            int tile = s2 >> 8;          // 0..5
            int l    = (s2 >> 2) & 63;
            int d    = s2 & 3;           // dword within frag
            int gate = tile >> 1, hfp = tile & 1;
            int rr = l & 15;
            int f  = (rr >> 2)*8 + hfp*4 + (rr & 3);
            int k  = (l >> 4)*8 + d*2;
            int row = gate*32 + f;
            dst[s2] = pkh2(W[row*32 + k], W[row*32 + k + 1]);
        }
    } else { // b == 43: combined input-weight f16 A-frags (+bias in const-1 col)
        unsigned* pa = (unsigned*)(ws + OFF_PWCA);
        unsigned* pm = (unsigned*)(ws + OFF_PWCM);
        for (int s = t; s < 3072; s += 256) {
            bool isA = (s < 1536);
            int s2 = isA ? s : s - 1536;
            unsigned* dst = isA ? pa : pm;
            int tile = s2 >> 8, l = (s2 >> 2) & 63, d = s2 & 3;
            int gate = tile >> 1, hfp = tile & 1;
            int rr = l & 15;
            int f = (rr >> 2)*8 + hfp*4 + (rr & 3);
            int o = gate*32 + f;
            int kb = (l >> 4)*8 + d*2;
            int ni = isA ? 7 : 4;
            float v[2];
            #pragma unroll
            for (int e = 0; e < 2; e++) {
                int k = kb + e;
                float acc = 0.f;
                if (k < ni) {
                    for (int m = 0; m < 32; m++)
                        acc += isA ? air_Wih[o*32+m]*enc_air_W[m*7+k]
                                   : m_Wih[o*32+m]*enc_m_W[m*4+k];
                } else if (k == ni) {
                    acc = isA ? air_bih[o] : m_bih[o];
                    for (int m = 0; m < 32; m++)
                        acc += isA ? air_Wih[o*32+m]*enc_air_b[m]
                                   : m_Wih[o*32+m]*enc_m_b[m];
                    if (gate < 2) acc += isA ? air_bhh[o] : m_bhh[o]; // r,z: fold bhh
                }
                v[e] = acc;
            }
            dst[s2] = pkh2(v[0], v[1]);
        }
        if (t < 32) {
            ws[OFF_BHNA + t] = air_bhh[64 + t];
            ws[OFF_BHNM + t] = m_bhh[64 + t];
        }
    }
}

// ---------------- GRU: 16 rows/wave via f16 MFMA, LDS-staged x --------------
// x inputs for the whole tile (16 rows x 128 t) are staged ONCE into LDS as
// pre-packed f16-pair B-frag dwords (XOR-swizzled, +zero slot for quads 1-3),
// removing global-load latency and the pack chain from the recurrent loop.
template<bool AIRT>
__device__ __forceinline__ void gru_tile(
    const float* __restrict__ obs, const float* __restrict__ rnn,
    const float* __restrict__ ws,
    unsigned short* __restrict__ feat, float* __restrict__ mask_f,
    float* __restrict__ nh_out, int tileIdx, unsigned* __restrict__ XH)
{
    const int lane = threadIdx.x & 63;
    const int col = lane & 15, quad = lane >> 4;
    const bool q0 = (quad == 0);

    // ---- weight frags (held in regs/AGPRs for the whole loop) ----
    const unsigned* pw = (const unsigned*)(ws + (AIRT ? OFF_PWHA : OFF_PWHM));
    const unsigned* pc = (const unsigned*)(ws + (AIRT ? OFF_PWCA : OFF_PWCM));
    f16x8 whf[6], wcf[6];
    #pragma unroll
    for (int i6 = 0; i6 < 6; i6++) {
        whf[i6] = __builtin_bit_cast(f16x8, *(const u32x4*)(pw + i6*256 + lane*4));
        wcf[i6] = __builtin_bit_cast(f16x8, *(const u32x4*)(pc + i6*256 + lane*4));
    }
    const float* bhnp = ws + (AIRT ? OFF_BHNA : OFF_BHNM) + quad*8;
    f32x4 bhn0 = *(const f32x4*)(bhnp);
    f32x4 bhn1 = *(const f32x4*)(bhnp + 4);

    int slot = 0, tb;
    if (AIRT) { tb = tileIdx*16; }
    else      { slot = tileIdx >> 7; tb = (tileIdx & 127)*16; }

    // ---- stage x (+mask for m) into LDS, pre-packed as f16 pairs ----
    {
        const int coff = AIRT ? 8 : slot*4;
        #pragma unroll 8
        for (int it = 0; it < 32; it++) {
            int s = it*64 + lane;
            int r = s >> 7, t = s & 127;
            const float* p = obs + (size_t)(tb + r)*1920 + t*15 + coff;
            unsigned d0, d1, d2, d3;
            if (AIRT) {
                d0 = pkh2(p[0], p[1]); d1 = pkh2(p[2], p[3]);
                d2 = pkh2(p[4], p[5]); d3 = pkh2(p[6], 1.0f);
            } else {
                float x0 = p[0], x1 = p[1], x2 = p[2], x3 = p[3];
                d0 = pkh2(x0, x1); d1 = pkh2(x2, x3);
                d2 = 0x00003C00u; d3 = 0u;     // (1.0h, 0) bias col, zeros
                bool ok = (fabsf(x0 - 1.f) <= 1.00001e-5f) && (fabsf(x1) <= 1e-8f) &&
                          (fabsf(x2 - 1.f) <= 1.00001e-5f) && (fabsf(x3) <= 1e-8f);
                mask_f[((size_t)(tb + r)*TT + t)*2 + slot] = ok ? 1.f : 0.f;
            }
            // u32 index, 16B-granular XOR swizzle on t's low 3 bits
            unsigned off = (unsigned)(r*512 + 4*(t ^ (r & 7)));
            *(u32x4*)(XH + off) = (u32x4){d0, d1, d2, d3};
        }
        if (lane == 0) *(u32x4*)(XH + 8192) = (u32x4){0u, 0u, 0u, 0u};
    }
    __syncthreads();

    // ---- per-lane row mapping ----
    int rowi = tileIdx*16 + col;          // air: r; m: i
    int hbase;
    size_t featOff = (size_t)rowi*(TT*32);
    if (AIRT) hbase = rowi*96;
    else      hbase = (rowi >> 1)*96 + 32 + (rowi & 1)*32;
    unsigned short* featp = feat + featOff + quad*8;

    // h state in D-layout: h0v = features quad*8+0..3, h1v = quad*8+4..7
    f32x4 h0v = *(const f32x4*)(rnn + hbase + quad*8);
    f32x4 h1v = *(const f32x4*)(rnn + hbase + quad*8 + 4);

    const int xk = col & 7;
    const unsigned bidx = (unsigned)col*512;
    u32x4 xc = *(const u32x4*)(XH + (q0 ? bidx + 4u*(unsigned)(0 ^ xk) : 8192u));

    #pragma unroll 1
    for (int t = 0; t < TT; t++) {
        const int tn = (t < TT-1) ? t+1 : t;
        u32x4 xnv = *(const u32x4*)(XH + (q0 ? bidx + 4u*(unsigned)(tn ^ xk) : 8192u));

        f16x8 xf = __builtin_bit_cast(f16x8, xc);

        // h B-frag: quad q supplies k = q*8..q*8+7 -> lane-local from h0v/h1v
        u32x4 hdv;
        hdv[0] = pkh2(h0v[0], h0v[1]); hdv[1] = pkh2(h0v[2], h0v[3]);
        hdv[2] = pkh2(h1v[0], h1v[1]); hdv[3] = pkh2(h1v[2], h1v[3]);
        f16x8 hff = __builtin_bit_cast(f16x8, hdv);

        const f32x4 z4 = {0.f, 0.f, 0.f, 0.f};
        f32x4 aR0 = mfma16f(whf[0], hff, mfma16f(wcf[0], xf, z4));
        f32x4 aR1 = mfma16f(whf[1], hff, mfma16f(wcf[1], xf, z4));
        f32x4 aZ0 = mfma16f(whf[2], hff, mfma16f(wcf[2], xf, z4));
        f32x4 aZ1 = mfma16f(whf[3], hff, mfma16f(wcf[3], xf, z4));
        f32x4 aXN0 = mfma16f(wcf[4], xf, z4);
        f32x4 aXN1 = mfma16f(wcf[5], xf, z4);
        f32x4 aHN0 = mfma16f(whf[4], hff, z4);
        f32x4 aHN1 = mfma16f(whf[5], hff, z4);

        #pragma unroll
        for (int s = 0; s < 4; s++) {
            {
                float r  = fast_rcp(1.f + __expf(-aR0[s]));
                float z  = fast_rcp(1.f + __expf(-aZ0[s]));
                float hn = aHN0[s] + bhn0[s];
                float pre = aXN0[s] + r*hn;
                float e2 = __expf(2.f*pre);
                float n  = 1.f - 2.f*fast_rcp(e2 + 1.f);
                h0v[s] = n + z*(h0v[s] - n);
            }
            {
                float r  = fast_rcp(1.f + __expf(-aR1[s]));
                float z  = fast_rcp(1.f + __expf(-aZ1[s]));
                float hn = aHN1[s] + bhn1[s];
                float pre = aXN1[s] + r*hn;
                float e2 = __expf(2.f*pre);
                float n  = 1.f - 2.f*fast_rcp(e2 + 1.f);
                h1v[s] = n + z*(h1v[s] - n);
            }
        }

        // bf16 feat store: 8 contiguous features per lane -> one dwordx4
        u32x4 fw;
        fw[0] = cvt_pk_bf16(h0v[0], h0v[1]); fw[1] = cvt_pk_bf16(h0v[2], h0v[3]);
        fw[2] = cvt_pk_bf16(h1v[0], h1v[1]); fw[3] = cvt_pk_bf16(h1v[2], h1v[3]);
        *(u32x4*)(featp + (size_t)t*32) = fw;

        xc = xnv;
    }
    *(f32x4*)(nh_out + hbase + quad*8)     = h0v;
    *(f32x4*)(nh_out + hbase + quad*8 + 4) = h1v;
}

__global__ __launch_bounds__(64, 1) void gru_kernel(
    const float* __restrict__ obs, const float* __restrict__ rnn,
    const float* __restrict__ ws,
    unsigned short* __restrict__ air_feat, unsigned short* __restrict__ m_feat,
    float* __restrict__ mask_f, float* __restrict__ nh_out)
{
    __shared__ unsigned XH[8196];   // 16 rows x 128 t x 4 dwords + zero slot
    int g = blockIdx.x;
    if (g < 128) gru_tile<true >(obs, rnn, ws, air_feat, mask_f, nh_out, g, XH);
    else         gru_tile<false>(obs, rnn, ws, m_feat,  mask_f, nh_out, g - 128, XH);
}

// ---------------- fused attention + MLP (bf16 MFMA, ct-split, pipelined) ----
__global__ __launch_bounds__(256) void fused_kernel(
    const unsigned short* __restrict__ air_feat, const unsigned short* __restrict__ m_feat,
    const float* __restrict__ mask_f,
    const unsigned short* __restrict__ wqkv, const float* __restrict__ attn_in_b,
    const unsigned short* __restrict__ wop,  const float* __restrict__ attn_out_b,
    const unsigned short* __restrict__ w0p, const float* __restrict__ b0,
    const unsigned short* __restrict__ w1p, const float* __restrict__ b1,
    const float* __restrict__ outW, const float* __restrict__ outb,
    float* __restrict__ val)
{
    __shared__ unsigned short A1[64*72];   // fusion: air 0-31, attn 32-63 (persists)
    __shared__ unsigned short U[64*264];   // phase1: AM(64*72)+CT(64*40); phase2: A2
    __shared__ float MS[128];
    __shared__ float PS[4][64];

    unsigned short* AM = U;
    unsigned short* CT = U + 64*72;
    unsigned short* A2 = U;

    const int tid  = threadIdx.x;
    const int lane = tid & 63;
    const int strip = tid >> 6;
    const int col  = lane & 15;
    const int quad = lane >> 4;
    const size_t n0 = (size_t)blockIdx.x * 64;

    // ---- attn weight frags: load BEFORE barrier (fly during staging drain)
    short8 wqf[2], wkf[2], wvf[2], wof[2];
    #pragma unroll
    for (int ct = 0; ct < 2; ct++) {
        wqf[ct] = *(const short8*)(wqkv + ((0+ct)*64 + lane)*8);
        wkf[ct] = *(const short8*)(wqkv + ((2+ct)*64 + lane)*8);
        wvf[ct] = *(const short8*)(wqkv + ((4+ct)*64 + lane)*8);
        wof[ct] = *(const short8*)(wop + (ct*64 + lane)*8);
    }

    // ---- stage bf16 feats directly ----
    {
        int row = tid >> 2, c0 = (tid & 3)*8;
        short8 va  = *(const short8*)(air_feat + (n0 + row)*32 + c0);
        *(short8*)&A1[row*72 + c0] = va;
        short8 vm1 = *(const short8*)(m_feat + (n0 + row)*32 + c0);
        *(short8*)&AM[row*72 + c0] = vm1;
        short8 vm2 = *(const short8*)(m_feat + ((size_t)NN + n0 + row)*32 + c0);
        *(short8*)&AM[row*72 + 32 + c0] = vm2;
        if (tid < 128) MS[tid] = mask_f[n0*2 + tid];
    }
    __syncthreads();

    // ---- attention (per-strip) ----
    {
        short8 a_air = *(const short8*)&A1[(strip*16 + col)*72 + quad*8];
        short8 a_m1  = *(const short8*)&AM[(strip*16 + col)*72 + quad*8];
        short8 a_m2  = *(const short8*)&AM[(strip*16 + col)*72 + 32 + quad*8];

        f32x4 q[2], k1[2], k2[2], v1[2], v2[2], ao[2];
        #pragma unroll
        for (int ct = 0; ct < 2; ct++) {
            f32x4 z = (f32x4){0.f,0.f,0.f,0.f};
            q[ct]  = __builtin_amdgcn_mfma_f32_16x16x32_bf16(a_air, wqf[ct], z, 0,0,0);
            k1[ct] = __builtin_amdgcn_mfma_f32_16x16x32_bf16(a_m1,  wkf[ct], z, 0,0,0);
            k2[ct] = __builtin_amdgcn_mfma_f32_16x16x32_bf16(a_m2,  wkf[ct], z, 0,0,0);
            v1[ct] = __builtin_amdgcn_mfma_f32_16x16x32_bf16(a_m1,  wvf[ct], z, 0,0,0);
            v2[ct] = __builtin_amdgcn_mfma_f32_16x16x32_bf16(a_m2,  wvf[ct], z, 0,0,0);
        }
        float bqr[2], bkr[2], bvr[2];
        #pragma unroll
        for (int ct = 0; ct < 2; ct++) {
            bqr[ct] = attn_in_b[ct*16 + col];
            bkr[ct] = attn_in_b[32 + ct*16 + col];
            bvr[ct] = attn_in_b[64 + ct*16 + col];
        }
        float p1s[2][4], p2s[2][4];
        #pragma unroll
        for (int ct = 0; ct < 2; ct++) {
            #pragma unroll
            for (int reg = 0; reg < 4; reg++) {
                float qq = q[ct][reg] + bqr[ct];
                float p1 = qq * (k1[ct][reg] + bkr[ct]);
                float p2 = qq * (k2[ct][reg] + bkr[ct]);
                #pragma unroll
                for (int m = 1; m < 16; m <<= 1) {
                    p1 += __shfl_xor(p1, m, 64);
                    p2 += __shfl_xor(p2, m, 64);
                }
                p1s[ct][reg] = p1; p2s[ct][reg] = p2;
            }
        }
        float bothm[4];
        #pragma unroll
        for (int reg = 0; reg < 4; reg++) {
            int rloc = strip*16 + quad*4 + reg;
            float m0v = MS[rloc*2], m1v = MS[rloc*2 + 1];
            bothm[reg] = (m0v > 0.5f && m1v > 0.5f) ? 1.f : 0.f;
            #pragma unroll
            for (int ct = 0; ct < 2; ct++) {
                float s1 = p1s[ct][reg]*0.25f + (m0v > 0.5f ? -1e9f : 0.f);
                float s2 = p2s[ct][reg]*0.25f + (m1v > 0.5f ? -1e9f : 0.f);
                float mx = fmaxf(s1, s2);
                float e1 = __expf(s1 - mx), e2 = __expf(s2 - mx);
                float inv = fast_rcp(e1 + e2);
                float ctxv = ((v1[ct][reg] + bvr[ct])*e1 +
                              (v2[ct][reg] + bvr[ct])*e2) * inv;
                CT[rloc*40 + ct*16 + col] = f2bf(ctxv);
            }
        }
        short8 a_ctx = *(const short8*)&CT[(strip*16 + col)*40 + quad*8];
        #pragma unroll
        for (int ct = 0; ct < 2; ct++) {
            f32x4 z = (f32x4){0.f,0.f,0.f,0.f};
            ao[ct] = __builtin_amdgcn_mfma_f32_16x16x32_bf16(a_ctx, wof[ct], z, 0,0,0);
        }
        float bor[2] = { attn_out_b[col], attn_out_b[16 + col] };
        #pragma unroll
        for (int reg = 0; reg < 4; reg++) {
            int rloc = strip*16 + quad*4 + reg;
            #pragma unroll
            for (int ct = 0; ct < 2; ct++) {
                float av = ao[ct][reg] + bor[ct];
                av = (bothm[reg] > 0.5f) ? 0.f : av;
                A1[rloc*72 + 32 + ct*16 + col] = f2bf(av);
            }
        }
    }
    __syncthreads();   // attention done; A1 complete; AM/CT now dead

    // per-lane bias / out-weight for this wave's 4 col-tiles
    float b0r[4], b1r[4], owr[4];
    #pragma unroll
    for (int c = 0; c < 4; c++) {
        int ct = strip*4 + c;
        b0r[c] = b0[ct*16 + col];
        b1r[c] = b1[ct*16 + col];
        owr[c] = outW[ct*16 + col];
    }
    const float outb0 = outb[0];

    // ---- layer 1: all 64 rows x this wave's 4 ct, K=64 (pipelined B-frags) --
    f32x4 acc1[4][4];   // [row-strip s][ct-local]
    #pragma unroll
    for (int s = 0; s < 4; s++)
        #pragma unroll
        for (int c = 0; c < 4; c++) acc1[s][c] = (f32x4){0.f,0.f,0.f,0.f};
    {
        short8 bfr[4], nbfr[4];
        #pragma unroll
        for (int c = 0; c < 4; c++)
            bfr[c] = *(const short8*)(w0p + ((0*16 + strip*4 + c)*64 + lane)*8);
        #pragma unroll
        for (int ks = 0; ks < 2; ks++) {
            if (ks < 1) {
                #pragma unroll
                for (int c = 0; c < 4; c++)
                    nbfr[c] = *(const short8*)(w0p + (((ks+1)*16 + strip*4 + c)*64 + lane)*8);
            }
            short8 a[4];
            #pragma unroll
            for (int s = 0; s < 4; s++)
                a[s] = *(const short8*)&A1[(s*16 + col)*72 + ks*32 + quad*8];
            #pragma unroll
            for (int c = 0; c < 4; c++)
                #pragma unroll
                for (int s = 0; s < 4; s++)
                    acc1[s][c] = __builtin_amdgcn_mfma_f32_16x16x32_bf16(a[s], bfr[c], acc1[s][c], 0, 0, 0);
            #pragma unroll
            for (int c = 0; c < 4; c++) bfr[c] = nbfr[c];
        }
    }
    __syncthreads();   // everyone done reading A1/U-phase1 before A2 overwrite
    #pragma unroll
    for (int s = 0; s < 4; s++) {
        #pragma unroll
        for (int c = 0; c < 4; c++) {
            int ct = strip*4 + c;
            #pragma unroll
            for (int reg = 0; reg < 4; reg++) {
                float h = acc1[s][c][reg] + b0r[c];
                h = (h > 0.f) ? h : 0.01f*h;
                A2[(s*16 + quad*4 + reg)*264 + ct*16 + col] = f2bf(h);
            }
        }
    }
    __syncthreads();

    // ---- layer 2: all 64 rows x this wave's 4 ct, K=256 (pipelined) ----
    f32x4 acc2[4][4];
    #pragma unroll
    for (int s = 0; s < 4; s++)
        #pragma unroll
        for (int c = 0; c < 4; c++) acc2[s][c] = (f32x4){0.f,0.f,0.f,0.f};
    {
        short8 bfr[4], nbfr[4];
        #pragma unroll
        for (int c = 0; c < 4; c++)
            bfr[c] = *(const short8*)(w1p + ((0*16 + strip*4 + c)*64 + lane)*8);
        #pragma unroll
        for (int ks = 0; ks < 8; ks++) {
            if (ks < 7) {
                #pragma unroll
                for (int c = 0; c < 4; c++)
                    nbfr[c] = *(const short8*)(w1p + (((ks+1)*16 + strip*4 + c)*64 + lane)*8);
            }
            short8 a[4];
            #pragma unroll
            for (int s = 0; s < 4; s++)
                a[s] = *(const short8*)&A2[(s*16 + col)*264 + ks*32 + quad*8];
            #pragma unroll
            for (int c = 0; c < 4; c++)
                #pragma unroll
                for (int s = 0; s < 4; s++)
                    acc2[s][c] = __builtin_amdgcn_mfma_f32_16x16x32_bf16(a[s], bfr[c], acc2[s][c], 0, 0, 0);
            #pragma unroll
            for (int c = 0; c < 4; c++) bfr[c] = nbfr[c];
        }
    }

    // ---- out layer: partial dot per wave, reduce across col-lanes + waves ----
    #pragma unroll
    for (int s = 0; s < 4; s++) {
        float pv[4];
        #pragma unroll
        for (int reg = 0; reg < 4; reg++) pv[reg] = 0.f;
        #pragma unroll
        for (int c = 0; c < 4; c++) {
            #pragma unroll
            for (int reg = 0; reg < 4; reg++) {
                float h = acc2[s][c][reg] + b1r[c];
                h = (h > 0.f) ? h : 0.01f*h;
                pv[reg] += h*owr[c];
            }
        }
        #pragma unroll
        for (int reg = 0; reg < 4; reg++) {
            #pragma unroll
            for (int m = 1; m < 16; m <<= 1)
                pv[reg] += __shfl_xor(pv[reg], m, 64);
            if (col == 0) PS[strip][s*16 + quad*4 + reg] = pv[reg];
        }
    }
    __syncthreads();
    if (tid < 64)
        val[n0 + tid] = PS[0][tid] + PS[1][tid] + PS[2][tid] + PS[3][tid] + outb0;
}

// ---------------- launch ---------------------------------------------------
extern "C" void kernel_launch(void* const* d_in, const int* in_sizes, int n_in,
                              void* d_out, int out_size, void* d_ws, size_t ws_size,
                              hipStream_t stream) {
    const float* obs        = (const float*)d_in[0];
    const float* rnn        = (const float*)d_in[1];
    const float* enc_air_W  = (const float*)d_in[2];
    const float* enc_air_b  = (const float*)d_in[3];
    const float* enc_m_W    = (const float*)d_in[4];
    const float* enc_m_b    = (const float*)d_in[5];
    const float* air_Wih    = (const float*)d_in[6];
    const float* air_Whh    = (const float*)d_in[7];
    const float* air_bih    = (const float*)d_in[8];
    const float* air_bhh    = (const float*)d_in[9];
    const float* m_Wih      = (const float*)d_in[10];
    const float* m_Whh      = (const float*)d_in[11];
    const float* m_bih      = (const float*)d_in[12];
    const float* m_bhh      = (const float*)d_in[13];
    const float* attn_in_w  = (const float*)d_in[14];
    const float* attn_in_b  = (const float*)d_in[15];
    const float* attn_out_w = (const float*)d_in[16];
    const float* attn_out_b = (const float*)d_in[17];
    const float* mlp_W0     = (const float*)d_in[18];
    const float* mlp_b0     = (const float*)d_in[19];
    const float* mlp_W1     = (const float*)d_in[20];
    const float* mlp_b1     = (const float*)d_in[21];
    const float* out_W      = (const float*)d_in[22];
    const float* out_b      = (const float*)d_in[23];

    float* ws  = (float*)d_ws;
    float* out = (float*)d_out;

    prep_kernel<<<44, 256, 0, stream>>>(enc_air_W, enc_air_b, enc_m_W, enc_m_b,
                                        air_Wih, air_bih, m_Wih, m_bih,
                                        air_Whh, m_Whh, air_bhh, m_bhh,
                                        mlp_W0, mlp_W1, attn_in_w, attn_out_w, ws);

    gru_kernel<<<384, 64, 0, stream>>>(obs, rnn, ws,
                                       (unsigned short*)(ws + OFF_AIRF),
                                       (unsigned short*)(ws + OFF_MF),
                                       ws + OFF_MASK, out + NVAL);

    fused_kernel<<<NN/64, 256, 0, stream>>>((const unsigned short*)(ws + OFF_AIRF),
                                            (const unsigned short*)(ws + OFF_MF),
                                            ws + OFF_MASK,
                                            (const unsigned short*)(ws + OFF_WQKV), attn_in_b,
                                            (const unsigned short*)(ws + OFF_WO),   attn_out_b,
                                            (const unsigned short*)(ws + OFF_W0P), mlp_b0,
                                            (const unsigned short*)(ws + OFF_W1P), mlp_b1,
                                            out_W, out_b, out);
}